// Round 19
// baseline (861.967 us; speedup 1.0000x reference)
//
#include <hip/hip_runtime.h>
#include <stdint.h>

// BitNet MLP, int8-MFMA. GEMM core v4.32: r12/r18 structure (PROVEN green)
// with v_mfma_i32_32x32x32_i8 instead of 16x16x64: +12% MFMA ceiling
// (4404 vs 3944 TOPS ubench), half the instructions per burst. Same LDS
// image/staging/swizzle (verified 0-conflict), same register budget
// (acc 4x4 x i32x16 = 256 AGPR), VOLATILE "+a" asm (order-pinning is
// correctness-load-bearing, r16/r17). 4-deep 32KB ring, vmcnt(16/8/0).
// Exact integer math; fp32 scale factors only.

typedef int i32x4 __attribute__((ext_vector_type(4)));
typedef int i32x16 __attribute__((ext_vector_type(16)));
typedef short s16x8 __attribute__((ext_vector_type(8)));

#define HD 4096
#define ID 11008
#define MD 4096          // B*S tokens
#define WN 45088768      // 11008*4096 per weight
#define N1 22016         // gate|up fused output width
#define QEPS 1e-5f
#define SQRT7 2.6457513110645907f

__device__ __forceinline__ void mfma32(i32x16& acc, i32x4 a, i32x4 b) {
  // VOLATILE: pins program order of MFMA cluster (correctness-critical)
  asm volatile("v_mfma_i32_32x32x32_i8 %0, %1, %2, %0"
               : "+a"(acc) : "v"(a), "v"(b));
}

__device__ __forceinline__ void gload_lds16(const char* g, char* l) {
  __builtin_amdgcn_global_load_lds((const __attribute__((address_space(1))) void*)g,
                                   (__attribute__((address_space(3))) void*)l, 16, 0, 0);
}

// ---- stage a 256row x 64B half-tile (16KB) with 256 threads, swizzled ------
// Thread t covers LDS bytes t*16 (+4KB per sweep): row=t>>2, slot=t&3.
// Image: lds[row][slot] = g[row][slot ^ ((row>>1)&3)]; source slot =
// (t&3)^((t>>3)&3); sweeps add 64 rows ((64>>1)&3==0, invariant).
// Verified SQ_LDS_BANK_CONFLICT==0 (r6/r7/r11/r12/r15/r18).
__device__ __forceinline__ void stage64q(const char* __restrict__ g, int ldk,
                                         char* lds, int t256) {
  int r = t256 >> 2, sl = (t256 & 3) ^ ((t256 >> 3) & 3);
  const char* gp = g + (size_t)r * ldk + (sl << 4);
  char* lp = lds + t256 * 16;
#pragma unroll
  for (int i = 0; i < 4; ++i) {
    gload_lds16(gp, lp);
    gp += (size_t)64 * ldk;
    lp += 4096;
  }
}

// ---- 256x256 x K core: 4-deep ring, counted vmcnt, 2 n-half phases --------
// Per-thread VMEM issue = 8/iter (4 A + 4 B). Entry-of-iter outstanding:
// stage(t+1)+stage(t+2) = 16 -> vmcnt(16) retires tile t. Tail 8 / 0.
// 32x32x32 frag read: lane reads row (base + l&31), k-slot (ks*2 + (l>>5))
// ^ swizzle ((l>>1)&3 == (row>>1)&3 since base is 32-multiple). Per 16-lane
// quarter: quad = (4*(row&1) + slot) & 7 covers all 8 -> conflict-free.
__device__ __forceinline__ void gemm_core(const char* __restrict__ ga,
                                          const char* __restrict__ gb,
                                          int ldk, int nt, char* lds,
                                          i32x16 (&acc)[4][4], int w, int l) {
  const int t256 = w * 64 + l;
  const int wr = (w >> 1) * 128, wc = (w & 1) * 128;
  const int l31 = l & 31, kh = l >> 5, sx = (l >> 1) & 3;
  const int slot0 = ((0 + kh) ^ sx) << 4;   // ks=0
  const int slot1 = ((2 + kh) ^ sx) << 4;   // ks=1
#pragma unroll
  for (int pt = 0; pt < 3; ++pt) {
    stage64q(ga + (size_t)pt * 64, ldk, lds + pt * 32768, t256);
    stage64q(gb + (size_t)pt * 64, ldk, lds + pt * 32768 + 16384, t256);
  }
  for (int t = 0; t < nt; ++t) {
    if (t + 2 < nt)      asm volatile("s_waitcnt vmcnt(16)" ::: "memory");
    else if (t + 1 < nt) asm volatile("s_waitcnt vmcnt(8)" ::: "memory");
    else                 asm volatile("s_waitcnt vmcnt(0)" ::: "memory");
    __builtin_amdgcn_s_barrier();
    const char* Ab = lds + (t & 3) * 32768;
    const char* Bb = Ab + 16384;
    char* pre = lds + ((t + 3) & 3) * 32768;  // slot last read at t-1 (drained)
    // ---- phase 0: stage A(t+3); read af (4 rb x 2 ks) + bf[0..1]; 16 MFMA --
    if (t + 3 < nt) stage64q(ga + (size_t)(t + 3) * 64, ldk, pre, t256);
    i32x4 af[4][2], bf[4][2];
#pragma unroll
    for (int rb = 0; rb < 4; ++rb) {
      const char* rp = Ab + (wr + rb * 32 + l31) * 64;
      af[rb][0] = *(const i32x4*)(rp + slot0);
      af[rb][1] = *(const i32x4*)(rp + slot1);
    }
#pragma unroll
    for (int nb = 0; nb < 2; ++nb) {
      const char* rp = Bb + (wc + nb * 32 + l31) * 64;
      bf[nb][0] = *(const i32x4*)(rp + slot0);
      bf[nb][1] = *(const i32x4*)(rp + slot1);
    }
#pragma unroll
    for (int nb = 0; nb < 2; ++nb)
#pragma unroll
      for (int rb = 0; rb < 4; ++rb) {
        mfma32(acc[rb][nb], af[rb][0], bf[nb][0]);
        mfma32(acc[rb][nb], af[rb][1], bf[nb][1]);
      }
    // ---- phase 1: stage B(t+3); read bf[2..3]; 16 MFMA ----
    if (t + 3 < nt) stage64q(gb + (size_t)(t + 3) * 64, ldk, pre + 16384, t256);
#pragma unroll
    for (int nb = 2; nb < 4; ++nb) {
      const char* rp = Bb + (wc + nb * 32 + l31) * 64;
      bf[nb][0] = *(const i32x4*)(rp + slot0);
      bf[nb][1] = *(const i32x4*)(rp + slot1);
    }
#pragma unroll
    for (int nb = 2; nb < 4; ++nb)
#pragma unroll
      for (int rb = 0; rb < 4; ++rb) {
        mfma32(acc[rb][nb], af[rb][0], bf[nb][0]);
        mfma32(acc[rb][nb], af[rb][1], bf[nb][1]);
      }
  }
}

// ---------------- GEMM1: xq x [wgq;wuq] -> C i16 ----------------------------
// C/D layout (guide-verified, dtype-independent): col = lane&31,
// row = (reg&3) + 8*(reg>>2) + 4*(lane>>5).
__global__ __launch_bounds__(256, 1) void gemm1_kernel(
    const char* __restrict__ A, const char* __restrict__ B, short* __restrict__ C) {
  __shared__ __align__(16) char lds[131072];
  int t = threadIdx.x, w = t >> 6, l = t & 63;
  // bn-major XCD mapping: on-XCD neighbors share B panels (1376 = 8*172)
  int wgid = ((int)blockIdx.x & 7) * 172 + ((int)blockIdx.x >> 3);
  int bm = wgid & 15, bn = wgid >> 4;  // bm in [0,16), bn in [0,86)
  i32x16 acc[4][4] = {};
  gemm_core(A + (size_t)bm * 256 * HD, B + (size_t)bn * 256 * HD, HD, HD / 64,
            lds, acc, w, l);
  int wr = (w >> 1) * 128, wc = (w & 1) * 128, l31 = l & 31, h4 = (l >> 5) * 4;
#pragma unroll
  for (int mi = 0; mi < 4; ++mi) {
#pragma unroll
    for (int q = 0; q < 4; ++q) {
      int rbase = bm * 256 + wr + mi * 32 + 8 * q + h4;
#pragma unroll
      for (int ni = 0; ni < 4; ++ni) {
        int col = bn * 256 + wc + ni * 32 + l31;
#pragma unroll
        for (int j = 0; j < 4; ++j) {
          int v = acc[mi][ni][q * 4 + j];
          v = v < -32768 ? -32768 : (v > 32767 ? 32767 : v);  // never triggers
          C[(size_t)(rbase + j) * N1 + col] = (short)v;
        }
      }
    }
  }
}

// ---------------- GEMM2: hq x wdq, fused scales -> f32 ----------------------
__global__ __launch_bounds__(256, 1) void gemm_down_kernel(
    const char* __restrict__ A, const char* __restrict__ B, float* __restrict__ out,
    const float* __restrict__ gammaF, const double* __restrict__ sums,
    const float* __restrict__ sd) {
  __shared__ __align__(16) char lds[131072];
  int t = threadIdx.x, w = t >> 6, l = t & 63;
  int wgid = ((int)blockIdx.x & 7) * 32 + ((int)blockIdx.x >> 3);  // 256 = 8*32
  int bm = wgid & 15, bn = wgid >> 4;
  i32x16 acc[4][4] = {};
  gemm_core(A + (size_t)bm * 256 * ID, B + (size_t)bn * 256 * ID, ID, ID / 64,
            lds, acc, w, l);
  float wdm = (float)(sums[2] * (1.0 / (double)WN)) * sd[0] * (1.f / 127.f);
  int wr = (w >> 1) * 128, wc = (w & 1) * 128, l31 = l & 31, h4 = (l >> 5) * 4;
#pragma unroll
  for (int mi = 0; mi < 4; ++mi) {
#pragma unroll
    for (int q = 0; q < 4; ++q) {
      int rbase = bm * 256 + wr + mi * 32 + 8 * q + h4;
      float4 g4 = *(const float4*)&gammaF[rbase];  // rows rbase..rbase+3
      float sa[4] = {g4.x * wdm, g4.y * wdm, g4.z * wdm, g4.w * wdm};
#pragma unroll
      for (int ni = 0; ni < 4; ++ni) {
        int col = bn * 256 + wc + ni * 32 + l31;
#pragma unroll
        for (int j = 0; j < 4; ++j)
          out[(size_t)(rbase + j) * HD + col] = (float)acc[mi][ni][q * 4 + j] * sa[j];
      }
    }
  }
}

// ---------------- helpers ----------------------------------------------------
__device__ __forceinline__ int pack4div(float4 v, float mul, float den, float lo, float hi) {
  int a = (int)fminf(fmaxf(rintf((v.x * mul) / den), lo), hi);
  int b = (int)fminf(fmaxf(rintf((v.y * mul) / den), lo), hi);
  int c = (int)fminf(fmaxf(rintf((v.z * mul) / den), lo), hi);
  int d = (int)fminf(fmaxf(rintf((v.w * mul) / den), lo), hi);
  return (a & 255) | ((b & 255) << 8) | ((c & 255) << 16) | ((d & 255) << 24);
}

// ---------------- absmean reductions (double atomics) -----------------------
__global__ __launch_bounds__(256) void abssum_kernel(const float4* __restrict__ w,
                                                     int n8, double* __restrict__ out) {
  float s = 0.f;
  int stride = gridDim.x * blockDim.x;
  for (int i = blockIdx.x * blockDim.x + threadIdx.x; i < n8; i += stride) {
    float4 v0 = w[i * 2], v1 = w[i * 2 + 1];
    s += fabsf(v0.x) + fabsf(v0.y) + fabsf(v0.z) + fabsf(v0.w);
    s += fabsf(v1.x) + fabsf(v1.y) + fabsf(v1.z) + fabsf(v1.w);
  }
#pragma unroll
  for (int off = 32; off > 0; off >>= 1) s += __shfl_down(s, off);
  __shared__ float red[4];
  int l = threadIdx.x & 63, wv = threadIdx.x >> 6;
  if (l == 0) red[wv] = s;
  __syncthreads();
  if (threadIdx.x == 0) {
    double tt = (double)red[0] + (double)red[1] + (double)red[2] + (double)red[3];
    atomicAdd(out, tt);
  }
}

// ---------------- per-row beta + int4 quant of x -> i8 ----------------------
__global__ __launch_bounds__(256) void quantx_kernel(const float* __restrict__ x,
                                                     char* __restrict__ xq,
                                                     float* __restrict__ scale_x) {
  int row = blockIdx.x;
  const float4* xr = (const float4*)(x + (size_t)row * HD);
  int t = threadIdx.x;
  float4 v[4];
  float s = 0.f;
#pragma unroll
  for (int k = 0; k < 4; ++k) {
    v[k] = xr[t + k * 256];
    s += fabsf(v[k].x) + fabsf(v[k].y) + fabsf(v[k].z) + fabsf(v[k].w);
  }
#pragma unroll
  for (int off = 32; off > 0; off >>= 1) s += __shfl_down(s, off);
  __shared__ float red[4];
  int l = t & 63, wv = t >> 6;
  if (l == 0) red[wv] = s;
  __syncthreads();
  float beta = (red[0] + red[1] + red[2] + red[3]) * (1.f / (float)HD);
  if (t == 0) scale_x[row] = (beta * SQRT7) / SQRT7;  // ref dequant scale
  float den = beta + QEPS;
  int* qr = (int*)(xq + (size_t)row * HD);
#pragma unroll
  for (int k = 0; k < 4; ++k)
    qr[t + k * 256] = pack4div(v[k], SQRT7, den, -8.f, 7.f);
}

// ---------------- ternary quant of a weight -> i8 {-1,0,1} ------------------
__global__ __launch_bounds__(256) void quantw_kernel(const float4* __restrict__ w,
                                                     int4* __restrict__ wq,
                                                     const double* __restrict__ sum) {
  float mean = (float)(*sum * (1.0 / (double)WN));
  float den = mean + QEPS;
  int n16 = WN / 16;
  int stride = gridDim.x * blockDim.x;
  for (int i = blockIdx.x * blockDim.x + threadIdx.x; i < n16; i += stride) {
    float4 v0 = w[i * 4 + 0], v1 = w[i * 4 + 1], v2 = w[i * 4 + 2], v3 = w[i * 4 + 3];
    int4 o;
    o.x = pack4div(v0, 1.f, den, -1.f, 1.f);
    o.y = pack4div(v1, 1.f, den, -1.f, 1.f);
    o.z = pack4div(v2, 1.f, den, -1.f, 1.f);
    o.w = pack4div(v3, 1.f, den, -1.f, 1.f);
    wq[i] = o;
  }
}

// -------- combine: relu^2*up, per-row gamma, int8 quant (one block per row) --
__global__ __launch_bounds__(256) void combine_kernel(
    const short* __restrict__ C, const float* __restrict__ scale_x,
    const double* __restrict__ sums, const float* __restrict__ sg,
    const float* __restrict__ su, float* __restrict__ gammaF,
    char* __restrict__ hq) {
  int row = blockIdx.x, t = threadIdx.x;
  float gm = (float)(sums[0] * (1.0 / (double)WN)) * sg[0];
  float um = (float)(sums[1] * (1.0 / (double)WN)) * su[0];
  float sx = scale_x[row];
  float sxg = sx * gm, sxu = sx * um;
  const s16x8* g8 = (const s16x8*)(C + (size_t)row * N1);
  const s16x8* u8 = (const s16x8*)(C + (size_t)row * N1 + ID);
  float hv[6][8];
  float m = 0.f;
#pragma unroll
  for (int k = 0; k < 6; ++k) {
    int c = t + k * 256;
    if (c < ID / 8) {
      s16x8 gi = __builtin_nontemporal_load(&g8[c]);
      s16x8 ui = __builtin_nontemporal_load(&u8[c]);
#pragma unroll
      for (int e = 0; e < 8; ++e) {
        float rg = fmaxf((float)gi[e] * sxg, 0.f);
        hv[k][e] = ((float)ui[e] * sxu) * (rg * rg);
        m = fmaxf(m, fabsf(hv[k][e]));
      }
    }
  }
#pragma unroll
  for (int off = 32; off > 0; off >>= 1) m = fmaxf(m, __shfl_xor(m, off));
  __shared__ float red[4];
  if ((t & 63) == 0) red[t >> 6] = m;
  __syncthreads();
  float gamma = fmaxf(fmaxf(red[0], red[1]), fmaxf(red[2], red[3]));
  if (t == 0) gammaF[row] = gamma;
  float den = gamma + QEPS;
  int2* hr = (int2*)(hq + (size_t)row * ID);
#pragma unroll
  for (int k = 0; k < 6; ++k) {
    int c = t + k * 256;
    if (c < ID / 8) {
      int2 o;
      o.x = pack4div(make_float4(hv[k][0], hv[k][1], hv[k][2], hv[k][3]), 127.f, den, -128.f, 127.f);
      o.y = pack4div(make_float4(hv[k][4], hv[k][5], hv[k][6], hv[k][7]), 127.f, den, -128.f, 127.f);
      hr[c] = o;
    }
  }
}

extern "C" void kernel_launch(void* const* d_in, const int* in_sizes, int n_in,
                              void* d_out, int out_size, void* d_ws, size_t ws_size,
                              hipStream_t stream) {
  (void)in_sizes; (void)n_in; (void)out_size; (void)ws_size;
  const float* x = (const float*)d_in[0];
  const float* w_gate = (const float*)d_in[1];
  const float* w_up = (const float*)d_in[2];
  const float* w_down = (const float*)d_in[3];
  const float* s_gate = (const float*)d_in[4];
  const float* s_up = (const float*)d_in[5];
  const float* s_down = (const float*)d_in[6];
  float* out = (float*)d_out;

  // ws layout (bytes):
  char* p = (char*)d_ws;
  double* sums = (double*)p;                        // 3 doubles
  float* gammaF = (float*)(p + 256);                // 4096 f32
  float* scale_x = (float*)(p + 256 + 16384);       // 4096 f32 -> head ends 33024
  char* xq = p + 33024;                             // 16,777,216
  char* wgq = xq + 16777216UL;                      // 45,088,768 (wuq contiguous after!)
  char* wuq = wgq + (size_t)WN;                     // => [wgq;wuq] = 22016 x 4096 i8
  char* wdq = wuq + (size_t)WN;
  short* C16 = (short*)(wdq + (size_t)WN);          // 180,355,072 (4096 x 22016 i16)
  char* hq = (char*)C16 + 180355072UL;              // 45,088,768  (~378 MB total)

  (void)hipMemsetAsync(p, 0, 256, stream);  // sums

  // w_down FIRST, gate/up LAST: at gemm1 launch the L3 still holds wgq/wuq.
  abssum_kernel<<<2048, 256, 0, stream>>>((const float4*)w_down, WN / 8, sums + 2);
  quantw_kernel<<<2048, 256, 0, stream>>>((const float4*)w_down, (int4*)wdq, sums + 2);
  abssum_kernel<<<2048, 256, 0, stream>>>((const float4*)w_gate, WN / 8, sums + 0);
  quantw_kernel<<<2048, 256, 0, stream>>>((const float4*)w_gate, (int4*)wgq, sums + 0);
  abssum_kernel<<<2048, 256, 0, stream>>>((const float4*)w_up, WN / 8, sums + 1);
  quantw_kernel<<<2048, 256, 0, stream>>>((const float4*)w_up, (int4*)wuq, sums + 1);

  quantx_kernel<<<MD, 256, 0, stream>>>(x, xq, scale_x);

  // fused gate|up: M=4096 (16 bm) x N=22016 (86 bn) -> 1376 blocks (= 8*172)
  gemm1_kernel<<<1376, 256, 0, stream>>>(xq, wgq, C16);

  combine_kernel<<<MD, 256, 0, stream>>>(C16, scale_x, sums, s_gate, s_up, gammaF, hq);

  // down: M=4096 x N=4096 -> 256 blocks (= 8*32), K=11008 (172 BK=64 tiles)
  gemm_down_kernel<<<256, 256, 0, stream>>>(hq, wdq, out, gammaF, sums, s_down);
}

// Round 20
// 823.835 us; speedup vs baseline: 1.0463x; 1.0463x over previous
//
#include <hip/hip_runtime.h>
#include <stdint.h>

// BitNet MLP, int8-MFMA. GEMM core v4b: r18 (PROVEN 830us green) + one tweak:
// ALL 16 fragment ds_reads issue up-front after the barrier (bf[4..7] hoisted
// above MFMA burst 0) so their latency drains under burst 0. Same barriers,
// same vmcnt(16/8/0) ladder, same 4-deep ring, VOLATILE "+a" MFMA asm
// (order-pinning is correctness-load-bearing, r16/r17), same verified
// 0-conflict swizzle. 16x16x64 MFMA (32x32 variant regressed, r19: LDS
// conflicts returned). Exact integer math; fp32 scale factors only.

typedef int i32x4 __attribute__((ext_vector_type(4)));
typedef short s16x8 __attribute__((ext_vector_type(8)));

#define HD 4096
#define ID 11008
#define MD 4096          // B*S tokens
#define WN 45088768      // 11008*4096 per weight
#define N1 22016         // gate|up fused output width
#define QEPS 1e-5f
#define SQRT7 2.6457513110645907f

__device__ __forceinline__ void mfma_a(i32x4& acc, i32x4 a, i32x4 b) {
  // VOLATILE: pins program order of MFMA cluster (correctness-critical, r16/r17)
  asm volatile("v_mfma_i32_16x16x64_i8 %0, %1, %2, %0"
               : "+a"(acc) : "v"(a), "v"(b));
}

__device__ __forceinline__ void gload_lds16(const char* g, char* l) {
  __builtin_amdgcn_global_load_lds((const __attribute__((address_space(1))) void*)g,
                                   (__attribute__((address_space(3))) void*)l, 16, 0, 0);
}

// ---- stage a 256row x 64B half-tile (16KB) with 256 threads, swizzled ------
// Thread t covers LDS bytes t*16 (+4KB per sweep): row=t>>2, slot=t&3.
// Image: lds[row][slot] = g[row][slot ^ ((row>>1)&3)]; source slot =
// (t&3)^((t>>3)&3); sweeps add 64 rows ((64>>1)&3==0, invariant).
// Verified SQ_LDS_BANK_CONFLICT==0 (r6/r7/r11/r12/r15/r18).
__device__ __forceinline__ void stage64q(const char* __restrict__ g, int ldk,
                                         char* lds, int t256) {
  int r = t256 >> 2, sl = (t256 & 3) ^ ((t256 >> 3) & 3);
  const char* gp = g + (size_t)r * ldk + (sl << 4);
  char* lp = lds + t256 * 16;
#pragma unroll
  for (int i = 0; i < 4; ++i) {
    gload_lds16(gp, lp);
    gp += (size_t)64 * ldk;
    lp += 4096;
  }
}

// ---- 256x256 x K core: 4-deep ring, counted vmcnt, 2 MFMA phases ----------
// Per-thread VMEM issue = 8/iter (4 A + 4 B). Entry-of-iter outstanding:
// stage(t+1)+stage(t+2) = 16 -> vmcnt(16) retires tile t. Tail 8 / 0.
__device__ __forceinline__ void gemm_core(const char* __restrict__ ga,
                                          const char* __restrict__ gb,
                                          int ldk, int nt, char* lds,
                                          i32x4 (&acc)[8][8], int w, int l) {
  const int t256 = w * 64 + l;
  const int wr = (w >> 1) * 128, wc = (w & 1) * 128;
  const int lr = l & 15;
  const int sw4 = (((l >> 4) ^ ((l >> 1) & 3)) << 4);
#pragma unroll
  for (int pt = 0; pt < 3; ++pt) {
    stage64q(ga + (size_t)pt * 64, ldk, lds + pt * 32768, t256);
    stage64q(gb + (size_t)pt * 64, ldk, lds + pt * 32768 + 16384, t256);
  }
  for (int t = 0; t < nt; ++t) {
    if (t + 2 < nt)      asm volatile("s_waitcnt vmcnt(16)" ::: "memory");
    else if (t + 1 < nt) asm volatile("s_waitcnt vmcnt(8)" ::: "memory");
    else                 asm volatile("s_waitcnt vmcnt(0)" ::: "memory");
    __builtin_amdgcn_s_barrier();
    const char* Ab = lds + (t & 3) * 32768;
    const char* Bb = Ab + 16384;
    char* pre = lds + ((t + 3) & 3) * 32768;  // slot last read at t-1 (drained)
    // ---- stage A(t+3); read ALL 16 frags up-front (bf[4..7] latency hides
    //      under MFMA burst 0, first consumed by burst 1) ----
    if (t + 3 < nt) stage64q(ga + (size_t)(t + 3) * 64, ldk, pre, t256);
    i32x4 af[8], bf[8];
#pragma unroll
    for (int i = 0; i < 8; ++i)
      af[i] = *(const i32x4*)(Ab + (wr + i * 16 + lr) * 64 + sw4);
#pragma unroll
    for (int i = 0; i < 8; ++i)
      bf[i] = *(const i32x4*)(Bb + (wc + i * 16 + lr) * 64 + sw4);
    // ---- burst 0: acc[:][0..3] ----
#pragma unroll
    for (int n = 0; n < 4; ++n)
#pragma unroll
      for (int m = 0; m < 8; ++m)
        mfma_a(acc[m][n], af[m], bf[n]);
    // ---- stage B(t+3); burst 1: acc[:][4..7] ----
    if (t + 3 < nt) stage64q(gb + (size_t)(t + 3) * 64, ldk, pre + 16384, t256);
#pragma unroll
    for (int n = 4; n < 8; ++n)
#pragma unroll
      for (int m = 0; m < 8; ++m)
        mfma_a(acc[m][n], af[m], bf[n]);
  }
}

// ---------------- GEMM1: xq x [wgq;wuq] -> C i16 ----------------------------
__global__ __launch_bounds__(256, 1) void gemm1_kernel(
    const char* __restrict__ A, const char* __restrict__ B, short* __restrict__ C) {
  __shared__ __align__(16) char lds[131072];
  int t = threadIdx.x, w = t >> 6, l = t & 63;
  // bn-major XCD mapping: on-XCD neighbors share B panels (1376 = 8*172)
  int wgid = ((int)blockIdx.x & 7) * 172 + ((int)blockIdx.x >> 3);
  int bm = wgid & 15, bn = wgid >> 4;  // bm in [0,16), bn in [0,86)
  i32x4 acc[8][8] = {};
  gemm_core(A + (size_t)bm * 256 * HD, B + (size_t)bn * 256 * HD, HD, HD / 64,
            lds, acc, w, l);
  int wr = (w >> 1) * 128, wc = (w & 1) * 128, lr = l & 15, lj = (l >> 4) * 4;
#pragma unroll
  for (int mi = 0; mi < 8; ++mi) {
    int row = bm * 256 + wr + mi * 16 + lj;
#pragma unroll
    for (int ni = 0; ni < 8; ++ni) {
      int col = bn * 256 + wc + ni * 16 + lr;
#pragma unroll
      for (int j = 0; j < 4; ++j) {
        int v = acc[mi][ni][j];
        v = v < -32768 ? -32768 : (v > 32767 ? 32767 : v);  // never triggers (|acc|<~2k)
        C[(size_t)(row + j) * N1 + col] = (short)v;
      }
    }
  }
}

// ---------------- GEMM2: hq x wdq, fused scales -> f32 ----------------------
__global__ __launch_bounds__(256, 1) void gemm_down_kernel(
    const char* __restrict__ A, const char* __restrict__ B, float* __restrict__ out,
    const float* __restrict__ gammaF, const double* __restrict__ sums,
    const float* __restrict__ sd) {
  __shared__ __align__(16) char lds[131072];
  int t = threadIdx.x, w = t >> 6, l = t & 63;
  int wgid = ((int)blockIdx.x & 7) * 32 + ((int)blockIdx.x >> 3);  // 256 = 8*32
  int bm = wgid & 15, bn = wgid >> 4;
  i32x4 acc[8][8] = {};
  gemm_core(A + (size_t)bm * 256 * ID, B + (size_t)bn * 256 * ID, ID, ID / 64,
            lds, acc, w, l);
  float wdm = (float)(sums[2] * (1.0 / (double)WN)) * sd[0] * (1.f / 127.f);
  int wr = (w >> 1) * 128, wc = (w & 1) * 128, lr = l & 15, lj = (l >> 4) * 4;
#pragma unroll
  for (int mi = 0; mi < 8; ++mi) {
    int row = bm * 256 + wr + mi * 16 + lj;
    float sa[4];
#pragma unroll
    for (int j = 0; j < 4; ++j) sa[j] = gammaF[row + j] * wdm;
#pragma unroll
    for (int ni = 0; ni < 8; ++ni) {
      int col = bn * 256 + wc + ni * 16 + lr;
#pragma unroll
      for (int j = 0; j < 4; ++j)
        out[(size_t)(row + j) * HD + col] = (float)acc[mi][ni][j] * sa[j];
    }
  }
}

// ---------------- helpers ----------------------------------------------------
__device__ __forceinline__ int pack4div(float4 v, float mul, float den, float lo, float hi) {
  int a = (int)fminf(fmaxf(rintf((v.x * mul) / den), lo), hi);
  int b = (int)fminf(fmaxf(rintf((v.y * mul) / den), lo), hi);
  int c = (int)fminf(fmaxf(rintf((v.z * mul) / den), lo), hi);
  int d = (int)fminf(fmaxf(rintf((v.w * mul) / den), lo), hi);
  return (a & 255) | ((b & 255) << 8) | ((c & 255) << 16) | ((d & 255) << 24);
}

// ---------------- absmean reductions (double atomics) -----------------------
__global__ __launch_bounds__(256) void abssum_kernel(const float4* __restrict__ w,
                                                     int n8, double* __restrict__ out) {
  float s = 0.f;
  int stride = gridDim.x * blockDim.x;
  for (int i = blockIdx.x * blockDim.x + threadIdx.x; i < n8; i += stride) {
    float4 v0 = w[i * 2], v1 = w[i * 2 + 1];
    s += fabsf(v0.x) + fabsf(v0.y) + fabsf(v0.z) + fabsf(v0.w);
    s += fabsf(v1.x) + fabsf(v1.y) + fabsf(v1.z) + fabsf(v1.w);
  }
#pragma unroll
  for (int off = 32; off > 0; off >>= 1) s += __shfl_down(s, off);
  __shared__ float red[4];
  int l = threadIdx.x & 63, wv = threadIdx.x >> 6;
  if (l == 0) red[wv] = s;
  __syncthreads();
  if (threadIdx.x == 0) {
    double tt = (double)red[0] + (double)red[1] + (double)red[2] + (double)red[3];
    atomicAdd(out, tt);
  }
}

// ---------------- per-row beta + int4 quant of x -> i8 ----------------------
__global__ __launch_bounds__(256) void quantx_kernel(const float* __restrict__ x,
                                                     char* __restrict__ xq,
                                                     float* __restrict__ scale_x) {
  int row = blockIdx.x;
  const float4* xr = (const float4*)(x + (size_t)row * HD);
  int t = threadIdx.x;
  float4 v[4];
  float s = 0.f;
#pragma unroll
  for (int k = 0; k < 4; ++k) {
    v[k] = xr[t + k * 256];
    s += fabsf(v[k].x) + fabsf(v[k].y) + fabsf(v[k].z) + fabsf(v[k].w);
  }
#pragma unroll
  for (int off = 32; off > 0; off >>= 1) s += __shfl_down(s, off);
  __shared__ float red[4];
  int l = t & 63, wv = t >> 6;
  if (l == 0) red[wv] = s;
  __syncthreads();
  float beta = (red[0] + red[1] + red[2] + red[3]) * (1.f / (float)HD);
  if (t == 0) scale_x[row] = (beta * SQRT7) / SQRT7;  // ref dequant scale
  float den = beta + QEPS;
  int* qr = (int*)(xq + (size_t)row * HD);
#pragma unroll
  for (int k = 0; k < 4; ++k)
    qr[t + k * 256] = pack4div(v[k], SQRT7, den, -8.f, 7.f);
}

// ---------------- ternary quant of a weight -> i8 {-1,0,1} ------------------
__global__ __launch_bounds__(256) void quantw_kernel(const float4* __restrict__ w,
                                                     int4* __restrict__ wq,
                                                     const double* __restrict__ sum) {
  float mean = (float)(*sum * (1.0 / (double)WN));
  float den = mean + QEPS;
  int n16 = WN / 16;
  int stride = gridDim.x * blockDim.x;
  for (int i = blockIdx.x * blockDim.x + threadIdx.x; i < n16; i += stride) {
    float4 v0 = w[i * 4 + 0], v1 = w[i * 4 + 1], v2 = w[i * 4 + 2], v3 = w[i * 4 + 3];
    int4 o;
    o.x = pack4div(v0, 1.f, den, -1.f, 1.f);
    o.y = pack4div(v1, 1.f, den, -1.f, 1.f);
    o.z = pack4div(v2, 1.f, den, -1.f, 1.f);
    o.w = pack4div(v3, 1.f, den, -1.f, 1.f);
    wq[i] = o;
  }
}

// -------- combine: relu^2*up, per-row gamma, int8 quant (one block per row) --
__global__ __launch_bounds__(256) void combine_kernel(
    const short* __restrict__ C, const float* __restrict__ scale_x,
    const double* __restrict__ sums, const float* __restrict__ sg,
    const float* __restrict__ su, float* __restrict__ gammaF,
    char* __restrict__ hq) {
  int row = blockIdx.x, t = threadIdx.x;
  float gm = (float)(sums[0] * (1.0 / (double)WN)) * sg[0];
  float um = (float)(sums[1] * (1.0 / (double)WN)) * su[0];
  float sx = scale_x[row];
  float sxg = sx * gm, sxu = sx * um;
  const s16x8* g8 = (const s16x8*)(C + (size_t)row * N1);
  const s16x8* u8 = (const s16x8*)(C + (size_t)row * N1 + ID);
  float hv[6][8];
  float m = 0.f;
#pragma unroll
  for (int k = 0; k < 6; ++k) {
    int c = t + k * 256;
    if (c < ID / 8) {
      s16x8 gi = __builtin_nontemporal_load(&g8[c]);
      s16x8 ui = __builtin_nontemporal_load(&u8[c]);
#pragma unroll
      for (int e = 0; e < 8; ++e) {
        float rg = fmaxf((float)gi[e] * sxg, 0.f);
        hv[k][e] = ((float)ui[e] * sxu) * (rg * rg);
        m = fmaxf(m, fabsf(hv[k][e]));
      }
    }
  }
#pragma unroll
  for (int off = 32; off > 0; off >>= 1) m = fmaxf(m, __shfl_xor(m, off));
  __shared__ float red[4];
  if ((t & 63) == 0) red[t >> 6] = m;
  __syncthreads();
  float gamma = fmaxf(fmaxf(red[0], red[1]), fmaxf(red[2], red[3]));
  if (t == 0) gammaF[row] = gamma;
  float den = gamma + QEPS;
  int2* hr = (int2*)(hq + (size_t)row * ID);
#pragma unroll
  for (int k = 0; k < 6; ++k) {
    int c = t + k * 256;
    if (c < ID / 8) {
      int2 o;
      o.x = pack4div(make_float4(hv[k][0], hv[k][1], hv[k][2], hv[k][3]), 127.f, den, -128.f, 127.f);
      o.y = pack4div(make_float4(hv[k][4], hv[k][5], hv[k][6], hv[k][7]), 127.f, den, -128.f, 127.f);
      hr[c] = o;
    }
  }
}

extern "C" void kernel_launch(void* const* d_in, const int* in_sizes, int n_in,
                              void* d_out, int out_size, void* d_ws, size_t ws_size,
                              hipStream_t stream) {
  (void)in_sizes; (void)n_in; (void)out_size; (void)ws_size;
  const float* x = (const float*)d_in[0];
  const float* w_gate = (const float*)d_in[1];
  const float* w_up = (const float*)d_in[2];
  const float* w_down = (const float*)d_in[3];
  const float* s_gate = (const float*)d_in[4];
  const float* s_up = (const float*)d_in[5];
  const float* s_down = (const float*)d_in[6];
  float* out = (float*)d_out;

  // ws layout (bytes):
  char* p = (char*)d_ws;
  double* sums = (double*)p;                        // 3 doubles
  float* gammaF = (float*)(p + 256);                // 4096 f32
  float* scale_x = (float*)(p + 256 + 16384);       // 4096 f32 -> head ends 33024
  char* xq = p + 33024;                             // 16,777,216
  char* wgq = xq + 16777216UL;                      // 45,088,768 (wuq contiguous after!)
  char* wuq = wgq + (size_t)WN;                     // => [wgq;wuq] = 22016 x 4096 i8
  char* wdq = wuq + (size_t)WN;
  short* C16 = (short*)(wdq + (size_t)WN);          // 180,355,072 (4096 x 22016 i16)
  char* hq = (char*)C16 + 180355072UL;              // 45,088,768  (~378 MB total)

  (void)hipMemsetAsync(p, 0, 256, stream);  // sums

  // w_down FIRST, gate/up LAST: at gemm1 launch the L3 still holds wgq/wuq.
  abssum_kernel<<<2048, 256, 0, stream>>>((const float4*)w_down, WN / 8, sums + 2);
  quantw_kernel<<<2048, 256, 0, stream>>>((const float4*)w_down, (int4*)wdq, sums + 2);
  abssum_kernel<<<2048, 256, 0, stream>>>((const float4*)w_gate, WN / 8, sums + 0);
  quantw_kernel<<<2048, 256, 0, stream>>>((const float4*)w_gate, (int4*)wgq, sums + 0);
  abssum_kernel<<<2048, 256, 0, stream>>>((const float4*)w_up, WN / 8, sums + 1);
  quantw_kernel<<<2048, 256, 0, stream>>>((const float4*)w_up, (int4*)wuq, sums + 1);

  quantx_kernel<<<MD, 256, 0, stream>>>(x, xq, scale_x);

  // fused gate|up: M=4096 (16 bm) x N=22016 (86 bn) -> 1376 blocks (= 8*172)
  gemm1_kernel<<<1376, 256, 0, stream>>>(xq, wgq, C16);

  combine_kernel<<<MD, 256, 0, stream>>>(C16, scale_x, sums, s_gate, s_up, gammaF, hq);

  // down: M=4096 x N=4096 -> 256 blocks (= 8*32), K=11008 (172 BK=64 tiles)
  gemm_down_kernel<<<256, 256, 0, stream>>>(hq, wdq, out, gammaF, sums, s_down);
}

// Round 22
// 817.538 us; speedup vs baseline: 1.0543x; 1.0077x over previous
//
#include <hip/hip_runtime.h>
#include <stdint.h>

// BitNet MLP, int8-MFMA. GEMM core v4b (r20 green: 823.8us, absmax 0.015625,
// 0 bank conflicts) + PERSISTENT gemm1: 256 blocks each loop a contiguous
// chunk of the 1376 tile-ids (eliminates the 96-block tail wave ~5-7%, and
// consecutive wgids share bn -> B panel stays L2-hot). __syncthreads()
// between tiles = full drain barrier (safe restage). Core untouched:
// 4 waves, per-wave 128x128, acc in AGPR via VOLATILE "+a" asm
// (order-pinning correctness-critical, r16/r17/r21), 4-deep 32KB ring,
// counted vmcnt(16/8/0), verified 0-conflict swizzle, 16x16x64 i8 MFMA.
// Exact integer math; fp32 scale factors only.

typedef int i32x4 __attribute__((ext_vector_type(4)));
typedef short s16x8 __attribute__((ext_vector_type(8)));

#define HD 4096
#define ID 11008
#define MD 4096          // B*S tokens
#define WN 45088768      // 11008*4096 per weight
#define N1 22016         // gate|up fused output width
#define QEPS 1e-5f
#define SQRT7 2.6457513110645907f

__device__ __forceinline__ void mfma_a(i32x4& acc, i32x4 a, i32x4 b) {
  // VOLATILE: pins program order of MFMA cluster (correctness-critical)
  asm volatile("v_mfma_i32_16x16x64_i8 %0, %1, %2, %0"
               : "+a"(acc) : "v"(a), "v"(b));
}

__device__ __forceinline__ void gload_lds16(const char* g, char* l) {
  __builtin_amdgcn_global_load_lds((const __attribute__((address_space(1))) void*)g,
                                   (__attribute__((address_space(3))) void*)l, 16, 0, 0);
}

// ---- stage a 256row x 64B half-tile (16KB) with 256 threads, swizzled ------
// Thread t covers LDS bytes t*16 (+4KB per sweep): row=t>>2, slot=t&3.
// Image: lds[row][slot] = g[row][slot ^ ((row>>1)&3)]; source slot =
// (t&3)^((t>>3)&3); sweeps add 64 rows ((64>>1)&3==0, invariant).
// Verified SQ_LDS_BANK_CONFLICT==0 (r6/r7/r11/r12/r15/r18/r20).
__device__ __forceinline__ void stage64q(const char* __restrict__ g, int ldk,
                                         char* lds, int t256) {
  int r = t256 >> 2, sl = (t256 & 3) ^ ((t256 >> 3) & 3);
  const char* gp = g + (size_t)r * ldk + (sl << 4);
  char* lp = lds + t256 * 16;
#pragma unroll
  for (int i = 0; i < 4; ++i) {
    gload_lds16(gp, lp);
    gp += (size_t)64 * ldk;
    lp += 4096;
  }
}

// ---- 256x256 x K core: 4-deep ring, counted vmcnt, 2 MFMA phases ----------
// Per-thread VMEM issue = 8/iter (4 A + 4 B). Entry-of-iter outstanding:
// stage(t+1)+stage(t+2) = 16 -> vmcnt(16) retires tile t. Tail 8 / 0.
__device__ __forceinline__ void gemm_core(const char* __restrict__ ga,
                                          const char* __restrict__ gb,
                                          int ldk, int nt, char* lds,
                                          i32x4 (&acc)[8][8], int w, int l) {
  const int t256 = w * 64 + l;
  const int wr = (w >> 1) * 128, wc = (w & 1) * 128;
  const int lr = l & 15;
  const int sw4 = (((l >> 4) ^ ((l >> 1) & 3)) << 4);
#pragma unroll
  for (int pt = 0; pt < 3; ++pt) {
    stage64q(ga + (size_t)pt * 64, ldk, lds + pt * 32768, t256);
    stage64q(gb + (size_t)pt * 64, ldk, lds + pt * 32768 + 16384, t256);
  }
  for (int t = 0; t < nt; ++t) {
    if (t + 2 < nt)      asm volatile("s_waitcnt vmcnt(16)" ::: "memory");
    else if (t + 1 < nt) asm volatile("s_waitcnt vmcnt(8)" ::: "memory");
    else                 asm volatile("s_waitcnt vmcnt(0)" ::: "memory");
    __builtin_amdgcn_s_barrier();
    const char* Ab = lds + (t & 3) * 32768;
    const char* Bb = Ab + 16384;
    char* pre = lds + ((t + 3) & 3) * 32768;  // slot last read at t-1 (drained)
    // ---- stage A(t+3); read ALL 16 frags up-front ----
    if (t + 3 < nt) stage64q(ga + (size_t)(t + 3) * 64, ldk, pre, t256);
    i32x4 af[8], bf[8];
#pragma unroll
    for (int i = 0; i < 8; ++i)
      af[i] = *(const i32x4*)(Ab + (wr + i * 16 + lr) * 64 + sw4);
#pragma unroll
    for (int i = 0; i < 8; ++i)
      bf[i] = *(const i32x4*)(Bb + (wc + i * 16 + lr) * 64 + sw4);
    // ---- burst 0: acc[:][0..3] ----
#pragma unroll
    for (int n = 0; n < 4; ++n)
#pragma unroll
      for (int m = 0; m < 8; ++m)
        mfma_a(acc[m][n], af[m], bf[n]);
    // ---- stage B(t+3); burst 1: acc[:][4..7] ----
    if (t + 3 < nt) stage64q(gb + (size_t)(t + 3) * 64, ldk, pre + 16384, t256);
#pragma unroll
    for (int n = 4; n < 8; ++n)
#pragma unroll
      for (int m = 0; m < 8; ++m)
        mfma_a(acc[m][n], af[m], bf[n]);
  }
}

// ---------------- GEMM1 (persistent): xq x [wgq;wuq] -> C i16 ---------------
// 256 blocks; block b handles contiguous wgids [start, start+cnt) (first 96
// blocks get 6, rest 5; 96*6 + 160*5 = 1376). Consecutive wgids share bn
// (bm = wgid&15 fastest) -> B panel L2-hot across the chunk.
__global__ __launch_bounds__(256, 1) void gemm1_kernel(
    const char* __restrict__ A, const char* __restrict__ B, short* __restrict__ C) {
  __shared__ __align__(16) char lds[131072];
  int t = threadIdx.x, w = t >> 6, l = t & 63;
  int b = (int)blockIdx.x;
  int start, cnt;
  if (b < 96) { start = b * 6; cnt = 6; }
  else        { start = 576 + (b - 96) * 5; cnt = 5; }
  for (int it = 0; it < cnt; ++it) {
    int wgid = start + it;
    int bm = wgid & 15, bn = wgid >> 4;  // bm in [0,16), bn in [0,86)
    __syncthreads();  // full drain (stores + LDS) before restaging the ring
    i32x4 acc[8][8] = {};
    gemm_core(A + (size_t)bm * 256 * HD, B + (size_t)bn * 256 * HD, HD, HD / 64,
              lds, acc, w, l);
    int wr = (w >> 1) * 128, wc = (w & 1) * 128, lr = l & 15, lj = (l >> 4) * 4;
#pragma unroll
    for (int mi = 0; mi < 8; ++mi) {
      int row = bm * 256 + wr + mi * 16 + lj;
#pragma unroll
      for (int ni = 0; ni < 8; ++ni) {
        int col = bn * 256 + wc + ni * 16 + lr;
#pragma unroll
        for (int j = 0; j < 4; ++j) {
          int v = acc[mi][ni][j];
          v = v < -32768 ? -32768 : (v > 32767 ? 32767 : v);  // never triggers
          C[(size_t)(row + j) * N1 + col] = (short)v;
        }
      }
    }
  }
}

// ---------------- GEMM2: hq x wdq, fused scales -> f32 ----------------------
__global__ __launch_bounds__(256, 1) void gemm_down_kernel(
    const char* __restrict__ A, const char* __restrict__ B, float* __restrict__ out,
    const float* __restrict__ gammaF, const double* __restrict__ sums,
    const float* __restrict__ sd) {
  __shared__ __align__(16) char lds[131072];
  int t = threadIdx.x, w = t >> 6, l = t & 63;
  int wgid = ((int)blockIdx.x & 7) * 32 + ((int)blockIdx.x >> 3);  // 256 = 8*32
  int bm = wgid & 15, bn = wgid >> 4;
  i32x4 acc[8][8] = {};
  gemm_core(A + (size_t)bm * 256 * ID, B + (size_t)bn * 256 * ID, ID, ID / 64,
            lds, acc, w, l);
  float wdm = (float)(sums[2] * (1.0 / (double)WN)) * sd[0] * (1.f / 127.f);
  int wr = (w >> 1) * 128, wc = (w & 1) * 128, lr = l & 15, lj = (l >> 4) * 4;
#pragma unroll
  for (int mi = 0; mi < 8; ++mi) {
    int row = bm * 256 + wr + mi * 16 + lj;
    float sa[4];
#pragma unroll
    for (int j = 0; j < 4; ++j) sa[j] = gammaF[row + j] * wdm;
#pragma unroll
    for (int ni = 0; ni < 8; ++ni) {
      int col = bn * 256 + wc + ni * 16 + lr;
#pragma unroll
      for (int j = 0; j < 4; ++j)
        out[(size_t)(row + j) * HD + col] = (float)acc[mi][ni][j] * sa[j];
    }
  }
}

// ---------------- helpers ----------------------------------------------------
__device__ __forceinline__ int pack4div(float4 v, float mul, float den, float lo, float hi) {
  int a = (int)fminf(fmaxf(rintf((v.x * mul) / den), lo), hi);
  int b = (int)fminf(fmaxf(rintf((v.y * mul) / den), lo), hi);
  int c = (int)fminf(fmaxf(rintf((v.z * mul) / den), lo), hi);
  int d = (int)fminf(fmaxf(rintf((v.w * mul) / den), lo), hi);
  return (a & 255) | ((b & 255) << 8) | ((c & 255) << 16) | ((d & 255) << 24);
}

// ---------------- absmean reductions (double atomics) -----------------------
__global__ __launch_bounds__(256) void abssum_kernel(const float4* __restrict__ w,
                                                     int n8, double* __restrict__ out) {
  float s = 0.f;
  int stride = gridDim.x * blockDim.x;
  for (int i = blockIdx.x * blockDim.x + threadIdx.x; i < n8; i += stride) {
    float4 v0 = w[i * 2], v1 = w[i * 2 + 1];
    s += fabsf(v0.x) + fabsf(v0.y) + fabsf(v0.z) + fabsf(v0.w);
    s += fabsf(v1.x) + fabsf(v1.y) + fabsf(v1.z) + fabsf(v1.w);
  }
#pragma unroll
  for (int off = 32; off > 0; off >>= 1) s += __shfl_down(s, off);
  __shared__ float red[4];
  int l = threadIdx.x & 63, wv = threadIdx.x >> 6;
  if (l == 0) red[wv] = s;
  __syncthreads();
  if (threadIdx.x == 0) {
    double tt = (double)red[0] + (double)red[1] + (double)red[2] + (double)red[3];
    atomicAdd(out, tt);
  }
}

// ---------------- per-row beta + int4 quant of x -> i8 ----------------------
__global__ __launch_bounds__(256) void quantx_kernel(const float* __restrict__ x,
                                                     char* __restrict__ xq,
                                                     float* __restrict__ scale_x) {
  int row = blockIdx.x;
  const float4* xr = (const float4*)(x + (size_t)row * HD);
  int t = threadIdx.x;
  float4 v[4];
  float s = 0.f;
#pragma unroll
  for (int k = 0; k < 4; ++k) {
    v[k] = xr[t + k * 256];
    s += fabsf(v[k].x) + fabsf(v[k].y) + fabsf(v[k].z) + fabsf(v[k].w);
  }
#pragma unroll
  for (int off = 32; off > 0; off >>= 1) s += __shfl_down(s, off);
  __shared__ float red[4];
  int l = t & 63, wv = t >> 6;
  if (l == 0) red[wv] = s;
  __syncthreads();
  float beta = (red[0] + red[1] + red[2] + red[3]) * (1.f / (float)HD);
  if (t == 0) scale_x[row] = (beta * SQRT7) / SQRT7;  // ref dequant scale
  float den = beta + QEPS;
  int* qr = (int*)(xq + (size_t)row * HD);
#pragma unroll
  for (int k = 0; k < 4; ++k)
    qr[t + k * 256] = pack4div(v[k], SQRT7, den, -8.f, 7.f);
}

// ---------------- ternary quant of a weight -> i8 {-1,0,1} ------------------
__global__ __launch_bounds__(256) void quantw_kernel(const float4* __restrict__ w,
                                                     int4* __restrict__ wq,
                                                     const double* __restrict__ sum) {
  float mean = (float)(*sum * (1.0 / (double)WN));
  float den = mean + QEPS;
  int n16 = WN / 16;
  int stride = gridDim.x * blockDim.x;
  for (int i = blockIdx.x * blockDim.x + threadIdx.x; i < n16; i += stride) {
    float4 v0 = w[i * 4 + 0], v1 = w[i * 4 + 1], v2 = w[i * 4 + 2], v3 = w[i * 4 + 3];
    int4 o;
    o.x = pack4div(v0, 1.f, den, -1.f, 1.f);
    o.y = pack4div(v1, 1.f, den, -1.f, 1.f);
    o.z = pack4div(v2, 1.f, den, -1.f, 1.f);
    o.w = pack4div(v3, 1.f, den, -1.f, 1.f);
    wq[i] = o;
  }
}

// -------- combine: relu^2*up, per-row gamma, int8 quant (one block per row) --
__global__ __launch_bounds__(256) void combine_kernel(
    const short* __restrict__ C, const float* __restrict__ scale_x,
    const double* __restrict__ sums, const float* __restrict__ sg,
    const float* __restrict__ su, float* __restrict__ gammaF,
    char* __restrict__ hq) {
  int row = blockIdx.x, t = threadIdx.x;
  float gm = (float)(sums[0] * (1.0 / (double)WN)) * sg[0];
  float um = (float)(sums[1] * (1.0 / (double)WN)) * su[0];
  float sx = scale_x[row];
  float sxg = sx * gm, sxu = sx * um;
  const s16x8* g8 = (const s16x8*)(C + (size_t)row * N1);
  const s16x8* u8 = (const s16x8*)(C + (size_t)row * N1 + ID);
  float hv[6][8];
  float m = 0.f;
#pragma unroll
  for (int k = 0; k < 6; ++k) {
    int c = t + k * 256;
    if (c < ID / 8) {
      s16x8 gi = __builtin_nontemporal_load(&g8[c]);
      s16x8 ui = __builtin_nontemporal_load(&u8[c]);
#pragma unroll
      for (int e = 0; e < 8; ++e) {
        float rg = fmaxf((float)gi[e] * sxg, 0.f);
        hv[k][e] = ((float)ui[e] * sxu) * (rg * rg);
        m = fmaxf(m, fabsf(hv[k][e]));
      }
    }
  }
#pragma unroll
  for (int off = 32; off > 0; off >>= 1) m = fmaxf(m, __shfl_xor(m, off));
  __shared__ float red[4];
  if ((t & 63) == 0) red[t >> 6] = m;
  __syncthreads();
  float gamma = fmaxf(fmaxf(red[0], red[1]), fmaxf(red[2], red[3]));
  if (t == 0) gammaF[row] = gamma;
  float den = gamma + QEPS;
  int2* hr = (int2*)(hq + (size_t)row * ID);
#pragma unroll
  for (int k = 0; k < 6; ++k) {
    int c = t + k * 256;
    if (c < ID / 8) {
      int2 o;
      o.x = pack4div(make_float4(hv[k][0], hv[k][1], hv[k][2], hv[k][3]), 127.f, den, -128.f, 127.f);
      o.y = pack4div(make_float4(hv[k][4], hv[k][5], hv[k][6], hv[k][7]), 127.f, den, -128.f, 127.f);
      hr[c] = o;
    }
  }
}

extern "C" void kernel_launch(void* const* d_in, const int* in_sizes, int n_in,
                              void* d_out, int out_size, void* d_ws, size_t ws_size,
                              hipStream_t stream) {
  (void)in_sizes; (void)n_in; (void)out_size; (void)ws_size;
  const float* x = (const float*)d_in[0];
  const float* w_gate = (const float*)d_in[1];
  const float* w_up = (const float*)d_in[2];
  const float* w_down = (const float*)d_in[3];
  const float* s_gate = (const float*)d_in[4];
  const float* s_up = (const float*)d_in[5];
  const float* s_down = (const float*)d_in[6];
  float* out = (float*)d_out;

  // ws layout (bytes):
  char* p = (char*)d_ws;
  double* sums = (double*)p;                        // 3 doubles
  float* gammaF = (float*)(p + 256);                // 4096 f32
  float* scale_x = (float*)(p + 256 + 16384);       // 4096 f32 -> head ends 33024
  char* xq = p + 33024;                             // 16,777,216
  char* wgq = xq + 16777216UL;                      // 45,088,768 (wuq contiguous after!)
  char* wuq = wgq + (size_t)WN;                     // => [wgq;wuq] = 22016 x 4096 i8
  char* wdq = wuq + (size_t)WN;
  short* C16 = (short*)(wdq + (size_t)WN);          // 180,355,072 (4096 x 22016 i16)
  char* hq = (char*)C16 + 180355072UL;              // 45,088,768  (~378 MB total)

  (void)hipMemsetAsync(p, 0, 256, stream);  // sums

  // w_down FIRST, gate/up LAST: at gemm1 launch the L3 still holds wgq/wuq.
  abssum_kernel<<<2048, 256, 0, stream>>>((const float4*)w_down, WN / 8, sums + 2);
  quantw_kernel<<<2048, 256, 0, stream>>>((const float4*)w_down, (int4*)wdq, sums + 2);
  abssum_kernel<<<2048, 256, 0, stream>>>((const float4*)w_gate, WN / 8, sums + 0);
  quantw_kernel<<<2048, 256, 0, stream>>>((const float4*)w_gate, (int4*)wgq, sums + 0);
  abssum_kernel<<<2048, 256, 0, stream>>>((const float4*)w_up, WN / 8, sums + 1);
  quantw_kernel<<<2048, 256, 0, stream>>>((const float4*)w_up, (int4*)wuq, sums + 1);

  quantx_kernel<<<MD, 256, 0, stream>>>(x, xq, scale_x);

  // fused gate|up: persistent grid of 256 blocks over 1376 tile-ids
  gemm1_kernel<<<256, 256, 0, stream>>>(xq, wgq, C16);

  combine_kernel<<<MD, 256, 0, stream>>>(C16, scale_x, sums, s_gate, s_up, gammaF, hq);

  // down: M=4096 x N=4096 -> 256 blocks (= 8*32), K=11008 (172 BK=64 tiles)
  gemm_down_kernel<<<256, 256, 0, stream>>>(hq, wdq, out, gammaF, sums, s_down);
}